// Round 4
// baseline (70.391 us; speedup 1.0000x reference)
//
#include <hip/hip_runtime.h>

#define N_CAND 8192
#define TILE   64                           // tile edge = wave width
#define NTILES (N_CAND / TILE)              // 128
#define NLIVE  (NTILES * (NTILES + 1) / 2)  // 8256 upper-triangle tiles
#define WPB    4                            // waves per block
#define NBLK   1024                         // 4 blocks/CU on 256 CUs, resident at t=0
#define NWAVE  (NBLK * WPB)                 // 4096 waves: 2 tiles each + 64 chunked strays

// Broadcast one lane's float to all lanes via SGPR (v_readlane_b32, SGPR lane idx ok).
__device__ __forceinline__ float readlane_f(float x, int lane) {
    return __int_as_float(__builtin_amdgcn_readlane(__float_as_int(x), lane));
}

// ---------------------------------------------------------------------------
// R13: two-kernel structure (R12's cooperative launch is NOT graph-capturable
// -> reverted). Inner math IDENTICAL to R11 (2 trans/pair, exp2 hoisted,
// -lis term factored). Structural changes:
//  - ROLLED j-loop with runtime [j0,j1): body ~2KB (was ~22KB fully unrolled
//    x2 branches) -> I$ pressure eliminated; readlane takes SGPR lane index.
//  - 1024 blocks x 4 waves: wave gw does tiles {gw, gw+4096}; the 64 stray
//    tiles are split into 256 16-column chunks, chunk c -> wave 16c+(c&3)
//    (spreads across all 4 SIMDs, <=1 chunk per block). Makespan 8.25tau vs
//    9tau (was +12% tail, now +3%).
//  - __launch_bounds__(256,4): VGPR cap 128 for deeper trans pipelining.
// ---------------------------------------------------------------------------
__device__ __forceinline__ float tile_range_sum(const float* __restrict__ logits,
                                                const int*   __restrict__ rankings,
                                                int t, int lane, int j0, int j1)
{
    // invert t = bj*(bj+1)/2 + bi, 0 <= bi <= bj < NTILES  (wave-uniform)
    t = __builtin_amdgcn_readfirstlane(t);
    int bj = (int)((__builtin_sqrtf(8.0f * (float)t + 1.0f) - 1.0f) * 0.5f);
    while ((bj + 1) * (bj + 2) / 2 <= t) ++bj;   // guard fp rounding
    while (bj * (bj + 1) / 2 > t)       --bj;
    const int bi = t - bj * (bj + 1) / 2;

    const float LOG2E = 1.4426950408889634f;
    const float INF   = __builtin_inff();

    const float lis = logits[bi * TILE + lane] * LOG2E;
    const float ri  = (float)rankings[bi * TILE + lane];
    const float ljs = logits[bj * TILE + lane] * LOG2E;
    const float rjv = (float)rankings[bj * TILE + lane];

    // exp2 hoisted out of the pair loop
    const float Ei  = __builtin_amdgcn_exp2f(lis);
    const float Ejv = __builtin_amdgcn_exp2f(ljs);

    float accL0 = 0.0f, accL1 = 0.0f, accL2 = 0.0f, accL3 = 0.0f;
    float accW0 = 0.0f, accW1 = 0.0f, accW2 = 0.0f, accW3 = 0.0f;

    if (bi != bj) {
        #pragma unroll 1
        for (int jj = j0; jj < j1; jj += 4) {
            const float Ej0 = readlane_f(Ejv, jj    ), rj0 = readlane_f(rjv, jj    );
            const float Ej1 = readlane_f(Ejv, jj + 1), rj1 = readlane_f(rjv, jj + 1);
            const float Ej2 = readlane_f(Ejv, jj + 2), rj2 = readlane_f(rjv, jj + 2);
            const float Ej3 = readlane_f(Ejv, jj + 3), rj3 = readlane_f(rjv, jj + 3);

            const float L0 = __builtin_amdgcn_logf(Ei + Ej0);
            const float L1 = __builtin_amdgcn_logf(Ei + Ej1);
            const float L2 = __builtin_amdgcn_logf(Ei + Ej2);
            const float L3 = __builtin_amdgcn_logf(Ei + Ej3);

            const float rs0 = (rj0 > ri) ? (ri + rj0) : INF;  // rcp(inf)=0 masks
            const float rs1 = (rj1 > ri) ? (ri + rj1) : INF;
            const float rs2 = (rj2 > ri) ? (ri + rj2) : INF;
            const float rs3 = (rj3 > ri) ? (ri + rj3) : INF;

            const float w0 = __builtin_amdgcn_rcpf(rs0);
            const float w1 = __builtin_amdgcn_rcpf(rs1);
            const float w2 = __builtin_amdgcn_rcpf(rs2);
            const float w3 = __builtin_amdgcn_rcpf(rs3);

            accL0 = fmaf(w0, L0, accL0);  accW0 += w0;
            accL1 = fmaf(w1, L1, accL1);  accW1 += w1;
            accL2 = fmaf(w2, L2, accL2);  accW2 += w2;
            accL3 = fmaf(w3, L3, accL3);  accW3 += w3;
        }
    } else {
        #pragma unroll 1
        for (int jj = j0; jj < j1; jj += 4) {
            const float Ej0 = readlane_f(Ejv, jj    ), rj0 = readlane_f(rjv, jj    );
            const float Ej1 = readlane_f(Ejv, jj + 1), rj1 = readlane_f(rjv, jj + 1);
            const float Ej2 = readlane_f(Ejv, jj + 2), rj2 = readlane_f(rjv, jj + 2);
            const float Ej3 = readlane_f(Ejv, jj + 3), rj3 = readlane_f(rjv, jj + 3);

            const float L0 = __builtin_amdgcn_logf(Ei + Ej0);
            const float L1 = __builtin_amdgcn_logf(Ei + Ej1);
            const float L2 = __builtin_amdgcn_logf(Ei + Ej2);
            const float L3 = __builtin_amdgcn_logf(Ei + Ej3);

            const float rs0 = ((jj     > lane) && (rj0 > ri)) ? (ri + rj0) : INF;
            const float rs1 = ((jj + 1 > lane) && (rj1 > ri)) ? (ri + rj1) : INF;
            const float rs2 = ((jj + 2 > lane) && (rj2 > ri)) ? (ri + rj2) : INF;
            const float rs3 = ((jj + 3 > lane) && (rj3 > ri)) ? (ri + rj3) : INF;

            const float w0 = __builtin_amdgcn_rcpf(rs0);
            const float w1 = __builtin_amdgcn_rcpf(rs1);
            const float w2 = __builtin_amdgcn_rcpf(rs2);
            const float w3 = __builtin_amdgcn_rcpf(rs3);

            accL0 = fmaf(w0, L0, accL0);  accW0 += w0;
            accL1 = fmaf(w1, L1, accL1);  accW1 += w1;
            accL2 = fmaf(w2, L2, accL2);  accW2 += w2;
            accL3 = fmaf(w3, L3, accL3);  accW3 += w3;
        }
    }

    const float accL = (accL0 + accL1) + (accL2 + accL3);
    const float accW = (accW0 + accW1) + (accW2 + accW3);
    return fmaf(-lis, accW, accL);   // factored -lis term, per lane
}

__global__ __launch_bounds__(256, 4) void ranknet_pairs_kernel(
    const float* __restrict__ logits,
    const int*   __restrict__ rankings,
    float*       __restrict__ partials)   // NBLK floats
{
    const int lane = threadIdx.x & 63;
    const int wave = threadIdx.x >> 6;
    const int gw   = __builtin_amdgcn_readfirstlane((int)blockIdx.x * WPB + wave);

    float lacc = 0.0f;
    // k=0: tile gw; k=1: tile gw+4096; k=2: stray 16-col chunk if this wave owns one.
    #pragma unroll 1
    for (int k = 0; k < 3; ++k) {
        int tt, jj0, jj1;
        bool live = true;
        if (k == 0)      { tt = gw;          jj0 = 0; jj1 = TILE; }
        else if (k == 1) { tt = gw + NWAVE;  jj0 = 0; jj1 = TILE; }
        else {
            const int c = gw >> 4;                    // candidate chunk id, c < 256
            live = ((gw & 15) == (c & 3));            // wave 16c+(c&3) owns chunk c
            tt   = 2 * NWAVE + (c >> 2);              // stray tile 8192 + c/4
            jj0  = (c & 3) * 16;                      // 16-column chunk
            jj1  = jj0 + 16;
        }
        if (live) lacc += tile_range_sum(logits, rankings, tt, lane, jj0, jj1);
    }

    // wave reduce — no LDS
    #pragma unroll
    for (int off = 32; off > 0; off >>= 1)
        lacc += __shfl_down(lacc, off, 64);

    __shared__ float s_w[WPB];
    if (lane == 0) s_w[wave] = lacc;
    __syncthreads();
    if (threadIdx.x == 0)
        partials[blockIdx.x] = (s_w[0] + s_w[1]) + (s_w[2] + s_w[3]);
}

// ---------------------------------------------------------------------------
// Pass 2: one 1024-thread block reduces the NBLK=1024 partials; applies ln2/N.
// ---------------------------------------------------------------------------
__global__ __launch_bounds__(1024) void ranknet_reduce_kernel(
    const float* __restrict__ partials,
    float*       __restrict__ out)
{
    __shared__ float s_part[16];
    const int tid = threadIdx.x;

    float acc = partials[tid];   // exactly 1024 partials

    #pragma unroll
    for (int off = 32; off > 0; off >>= 1)
        acc += __shfl_down(acc, off, 64);
    if ((tid & 63) == 0) s_part[tid >> 6] = acc;
    __syncthreads();
    if (tid == 0) {
        float s = 0.0f;
        #pragma unroll
        for (int w = 0; w < 16; ++w) s += s_part[w];
        const float LN2 = 0.6931471805599453f;
        out[0] = s * (LN2 / (float)N_CAND);
    }
}

extern "C" void kernel_launch(void* const* d_in, const int* in_sizes, int n_in,
                              void* d_out, int out_size, void* d_ws, size_t ws_size,
                              hipStream_t stream)
{
    const float* logits   = (const float*)d_in[0];
    const int*   rankings = (const int*)  d_in[1];
    float*       out      = (float*)d_out;
    float*       partials = (float*)d_ws;   // NBLK floats = 4 KB

    ranknet_pairs_kernel<<<dim3(NBLK), dim3(256), 0, stream>>>(logits, rankings, partials);
    ranknet_reduce_kernel<<<1, 1024, 0, stream>>>(partials, out);
}